// Round 6
// baseline (186.987 us; speedup 1.0000x reference)
//
#include <hip/hip_runtime.h>

// QRNN: B=8 T=2048 C=512 U=512 W=2
// R7 (3rd resubmit — three GPUAcquisitionTimeouts in a row, kernel never ran):
//  - phaseB: separate hstart buffer (no in-place aliasing) + explicit 8-deep
//    batched prefetch -> chain latency amortized 8x.
//  - phaseA/C: full unroll of CL=16 loop (all chunk loads independent in-wave).
//  - conv_x/conv_k/gemm: unchanged (gemm harness-proven ~67us).

#define Bn 8
#define Tn 2048
#define Cn 512
#define Un 512
#define Nn 1536
#define Kn 1024
#define Mn (Bn * Tn)
#define NC 128  // chunks per sequence
#define CL 16   // chunk length (NC*CL == Tn)

using bf16x8 = __attribute__((ext_vector_type(8))) __bf16;
using f32x4  = __attribute__((ext_vector_type(4))) float;
using ushort8v = __attribute__((ext_vector_type(8))) unsigned short;

__device__ __forceinline__ void async16(const void* g, void* l) {
  __builtin_amdgcn_global_load_lds((const __attribute__((address_space(1))) void*)g,
                                   (__attribute__((address_space(3))) void*)l, 16, 0, 0);
}

__device__ __forceinline__ unsigned short f2bf(float v) {
  union { float f; unsigned u; } c; c.f = v;
  unsigned u = c.u;
  return (unsigned short)((u + 0x7fffu + ((u >> 16) & 1u)) >> 16);  // RNE
}

__device__ __forceinline__ float bf2f(unsigned short h) {
  union { unsigned u; float f; } c; c.u = ((unsigned)h) << 16;
  return c.f;
}

__device__ __forceinline__ float fast_sigmoid(float x) {
  float e = __builtin_amdgcn_exp2f(-1.4426950408889634f * x);
  return __builtin_amdgcn_rcpf(1.0f + e);
}
__device__ __forceinline__ float fast_tanh(float x) {
  float e = __builtin_amdgcn_exp2f(-2.8853900817779268f * x);
  return 2.0f * __builtin_amdgcn_rcpf(1.0f + e) - 1.0f;
}

// ---- 1. x -> padded bf16 (8 elems / thread) ---------------------------------
__global__ __launch_bounds__(256) void conv_x(const float* __restrict__ x,
                                              unsigned short* __restrict__ xb) {
  int idx = blockIdx.x * 256 + threadIdx.x;   // over B*(T+1)*C/8
  int c8  = idx & 63;                         // C/8 = 64
  int row = idx >> 6;                         // b*(T+1)+t
  int b   = row / (Tn + 1);
  int t   = row - b * (Tn + 1);
  ushort8v ov;
  if (t == 0) {
#pragma unroll
    for (int i = 0; i < 8; i++) ov[i] = 0;
  } else {
    const float* xp = x + (size_t)(b * Tn + t - 1) * Cn + c8 * 8;
    float4 v0 = *(const float4*)xp;
    float4 v1 = *(const float4*)(xp + 4);
    ov[0] = f2bf(v0.x); ov[1] = f2bf(v0.y); ov[2] = f2bf(v0.z); ov[3] = f2bf(v0.w);
    ov[4] = f2bf(v1.x); ov[5] = f2bf(v1.y); ov[6] = f2bf(v1.z); ov[7] = f2bf(v1.w);
  }
  *(ushort8v*)(xb + (size_t)row * Cn + c8 * 8) = ov;
}

// ---- 2. kernel -> bf16 transposed [N][K] (unchanged) ------------------------
__global__ __launch_bounds__(256) void conv_k(const float* __restrict__ kern,
                                              unsigned short* __restrict__ kT) {
  __shared__ float tile[32][33];
  int kb = blockIdx.x, nb = blockIdx.y;       // grid (32, 48)
  int tx = threadIdx.x & 31, ty = threadIdx.x >> 5;
#pragma unroll
  for (int i = 0; i < 4; i++)
    tile[ty + i * 8][tx] = kern[(size_t)(kb * 32 + ty + i * 8) * Nn + nb * 32 + tx];
  __syncthreads();
#pragma unroll
  for (int i = 0; i < 4; i++) {
    int n = nb * 32 + ty + i * 8;
    int k = kb * 32 + tx;
    kT[(size_t)n * Kn + k] = f2bf(tile[tx][ty + i * 8]);
  }
}

// ---- 3. MFMA GEMM + activation epilogue (unchanged from R5) -----------------
__global__ __launch_bounds__(256) void gemm_gates(const unsigned short* __restrict__ xb,
                                                  const unsigned short* __restrict__ kT,
                                                  const float* __restrict__ bias,
                                                  unsigned short* __restrict__ gates) {
  __shared__ unsigned short As[128 * 64];   // 16 KB
  __shared__ unsigned short Bs[128 * 64];   // 16 KB
  const int tid = threadIdx.x;
  const int m0 = blockIdx.x * 128;
  const int n0 = blockIdx.y * 128;
  const int batch = m0 / Tn;                // tiles never cross batch
  const int lane = tid & 63;
  const int w = tid >> 6, wr = w >> 1, wc = w & 1;

  const int srow = (w << 3) + (lane >> 3);        // + j*32 per call
  const int skq  = (lane & 7) ^ (lane >> 3);      // frag index this lane fetches
  const unsigned short* aStage = xb + (size_t)(m0 + batch + srow) * Cn + (skq << 3);
  const unsigned short* bStage = kT + (size_t)(n0 + srow) * Kn + (skq << 3);

  f32x4 zero = {0.f, 0.f, 0.f, 0.f};
  f32x4 acc[4][4];
#pragma unroll
  for (int i = 0; i < 4; i++)
#pragma unroll
    for (int j = 0; j < 4; j++) acc[i][j] = zero;

  const int rA0 = wr * 64 + (lane & 15);    // frag row base for A reads
  const int rB0 = wc * 64 + (lane & 15);
  const int swz = lane & 7;                 // row&7 for frag reads

  for (int k0 = 0; k0 < Kn; k0 += 64) {
#pragma unroll
    for (int j = 0; j < 4; j++) {
      async16(aStage + (size_t)(j << 5) * Cn + k0, &As[(j * 256 + tid) * 8]);
      async16(bStage + (size_t)(j << 5) * Kn + k0, &Bs[(j * 256 + tid) * 8]);
    }
    __builtin_amdgcn_s_waitcnt(0);
    __syncthreads();

#pragma unroll
    for (int ks = 0; ks < 2; ks++) {
      const int col = (((ks << 2) + (lane >> 4)) ^ swz) << 3;  // swizzled 16B col
      bf16x8 af[4], bf[4];
#pragma unroll
      for (int i = 0; i < 4; i++) {
        af[i] = *(const bf16x8*)&As[(rA0 + i * 16) * 64 + col];
        bf[i] = *(const bf16x8*)&Bs[(rB0 + i * 16) * 64 + col];
      }
#pragma unroll
      for (int i = 0; i < 4; i++)
#pragma unroll
        for (int j = 0; j < 4; j++)
          acc[i][j] = __builtin_amdgcn_mfma_f32_16x16x32_bf16(af[i], bf[j], acc[i][j], 0, 0, 0);
    }
    __syncthreads();
  }

  const int region = blockIdx.y >> 2;       // 0=z(tanh) 1=f(sig) 2=o(sig)
  const int rowB = wr * 64 + (lane >> 4) * 4;
  const int colB = wc * 64 + (lane & 15);
#pragma unroll
  for (int i = 0; i < 4; i++)
#pragma unroll
    for (int j = 0; j < 4; j++)
#pragma unroll
      for (int r = 0; r < 4; r++) {
        int mm = m0 + rowB + i * 16 + r;
        int nn = n0 + colB + j * 16;
        float g = acc[i][j][r] + bias[nn];
        float a = (region == 0) ? fast_tanh(g) : fast_sigmoid(g);
        gates[(size_t)mm * Nn + nn] = f2bf(a);
      }
}

// ---- 4. per-chunk affine (a, bv): h_end = a*h_start + bv --------------------
// grid B*NC = 1024 blocks x 128 threads; each thread owns 4 u's (ushort4 loads)
__global__ __launch_bounds__(128) void scan_phaseA(const unsigned short* __restrict__ gates,
                                                   float* __restrict__ aArr,
                                                   float* __restrict__ bArr) {
  int chunk = blockIdx.x;                   // b*NC + c
  int u0 = threadIdx.x << 2;
  int b = chunk >> 7, c = chunk & (NC - 1);
  const unsigned short* gp = gates + (size_t)(b * Tn + c * CL) * Nn + u0;
  float a[4] = {1.f, 1.f, 1.f, 1.f}, bv[4] = {0.f, 0.f, 0.f, 0.f};
#pragma unroll
  for (int t = 0; t < CL; t++) {
    ushort4 zv = *(const ushort4*)(gp);
    ushort4 fv = *(const ushort4*)(gp + Un);
    float z[4] = {bf2f(zv.x), bf2f(zv.y), bf2f(zv.z), bf2f(zv.w)};
    float f[4] = {bf2f(fv.x), bf2f(fv.y), bf2f(fv.z), bf2f(fv.w)};
#pragma unroll
    for (int i = 0; i < 4; i++) {
      a[i] *= f[i];
      bv[i] = f[i] * bv[i] + (1.0f - f[i]) * z[i];
    }
    gp += Nn;
  }
  float4 av = {a[0], a[1], a[2], a[3]};
  float4 bvv = {bv[0], bv[1], bv[2], bv[3]};
  *(float4*)(aArr + (size_t)chunk * Un + u0) = av;
  *(float4*)(bArr + (size_t)chunk * Un + u0) = bvv;
}

// ---- 5. scan over chunks; 8-deep batched prefetch, separate hstart ----------
// grid 8 x 128; each thread owns 4 u's
__global__ __launch_bounds__(128) void scan_phaseB(const float* __restrict__ aArr,
                                                   const float* __restrict__ bArr,
                                                   const float* __restrict__ init,
                                                   float* __restrict__ hstart) {
  int idx = blockIdx.x * 128 + threadIdx.x; // 0..1023 = (b, u/4)
  int b = idx >> 7;
  int u0 = (idx & 127) << 2;
  float4 h = *(const float4*)(init + u0);
  for (int c0 = 0; c0 < NC; c0 += 8) {
    float4 av[8], bv[8];
#pragma unroll
    for (int j = 0; j < 8; j++) {
      size_t offc = (size_t)(b * NC + c0 + j) * Un + u0;
      av[j] = *(const float4*)(aArr + offc);
      bv[j] = *(const float4*)(bArr + offc);
    }
#pragma unroll
    for (int j = 0; j < 8; j++) {
      size_t offc = (size_t)(b * NC + c0 + j) * Un + u0;
      *(float4*)(hstart + offc) = h;        // h_start for chunk c0+j
      h.x = av[j].x * h.x + bv[j].x;
      h.y = av[j].y * h.y + bv[j].y;
      h.z = av[j].z * h.z + bv[j].z;
      h.w = av[j].w * h.w + bv[j].w;
    }
  }
}

// ---- 6. replay chunk with known h_start, apply output gate ------------------
// grid B*NC = 1024 blocks x 128 threads; 4 u's/thread; float4 stores
__global__ __launch_bounds__(128) void scan_phaseC(const unsigned short* __restrict__ gates,
                                                   const float* __restrict__ hstart,
                                                   float* __restrict__ out) {
  int chunk = blockIdx.x;
  int u0 = threadIdx.x << 2;
  int b = chunk >> 7, c = chunk & (NC - 1);
  const unsigned short* gp = gates + (size_t)(b * Tn + c * CL) * Nn + u0;
  float* op = out + (size_t)(b * Tn + c * CL) * Un + u0;
  float4 hv = *(const float4*)(hstart + (size_t)chunk * Un + u0);
  float h[4] = {hv.x, hv.y, hv.z, hv.w};
#pragma unroll
  for (int t = 0; t < CL; t++) {
    ushort4 zv = *(const ushort4*)(gp);
    ushort4 fv = *(const ushort4*)(gp + Un);
    ushort4 ov = *(const ushort4*)(gp + 2 * Un);
    float z[4] = {bf2f(zv.x), bf2f(zv.y), bf2f(zv.z), bf2f(zv.w)};
    float f[4] = {bf2f(fv.x), bf2f(fv.y), bf2f(fv.z), bf2f(fv.w)};
    float o[4] = {bf2f(ov.x), bf2f(ov.y), bf2f(ov.z), bf2f(ov.w)};
    float4 res;
#pragma unroll
    for (int i = 0; i < 4; i++) {
      h[i] = f[i] * h[i] + (1.0f - f[i]) * z[i];
      res[i] = h[i] * o[i];
    }
    *(float4*)op = res;
    gp += Nn;
    op += Un;
  }
}

extern "C" void kernel_launch(void* const* d_in, const int* in_sizes, int n_in,
                              void* d_out, int out_size, void* d_ws, size_t ws_size,
                              hipStream_t stream) {
  const float* x    = (const float*)d_in[0];  // [8,2048,512]
  const float* kern = (const float*)d_in[1];  // [2,512,1536]
  const float* bias = (const float*)d_in[2];  // [1536]
  const float* init = (const float*)d_in[3];  // [1,512]
  float* out = (float*)d_out;                 // [8,2048,512]

  char* ws = (char*)d_ws;
  unsigned short* xb = (unsigned short*)ws;                      // 16.8 MB
  size_t off = (size_t)Bn * (Tn + 1) * Cn * 2;
  unsigned short* kT = (unsigned short*)(ws + off);              // 3.1 MB
  off += (size_t)Nn * Kn * 2;
  unsigned short* gates = (unsigned short*)(ws + off);           // 50.3 MB (bf16)
  off += (size_t)Mn * Nn * 2;
  float* aArr = (float*)(ws + off);  off += (size_t)Bn * NC * Un * 4;   // 2 MB
  float* bArr = (float*)(ws + off);  off += (size_t)Bn * NC * Un * 4;   // 2 MB
  float* hstart = (float*)(ws + off);                                   // 2 MB

  conv_x<<<(Bn * (Tn + 1) * Cn / 8) / 256, 256, 0, stream>>>(x, xb);
  conv_k<<<dim3(32, 48), 256, 0, stream>>>(kern, kT);
  gemm_gates<<<dim3(Mn / 128, Nn / 128), 256, 0, stream>>>(xb, kT, bias, gates);
  scan_phaseA<<<Bn * NC, 128, 0, stream>>>(gates, aArr, bArr);
  scan_phaseB<<<(Bn * Un / 4) / 128, 128, 0, stream>>>(aArr, bArr, init, hstart);
  scan_phaseC<<<Bn * NC, 128, 0, stream>>>(gates, hstart, out);
}

// Round 11
// 185.277 us; speedup vs baseline: 1.0092x; 1.0092x over previous
//
#include <hip/hip_runtime.h>

// QRNN: B=8 T=2048 C=512 U=512 W=2
// R8 (5th submit — repeated GPUAcquisitionTimeouts, kernel has never run):
//  - phaseA/C: 1 u/thread SCALAR loads (still one 128B txn/wave/gate),
//    grid 2048 blocks x 256 thr = 524288 threads = full occupancy (G11).
//    CL=16 keeps the serial loop short; latency hidden by TLP not ILP.
//  - phaseB: R7's 8-deep batched form (measured-neutral, kept).
//  - conv_x/conv_k/gemm: unchanged (gemm harness-proven ~67us).

#define Bn 8
#define Tn 2048
#define Cn 512
#define Un 512
#define Nn 1536
#define Kn 1024
#define Mn (Bn * Tn)
#define NC 128  // chunks per sequence
#define CL 16   // chunk length (NC*CL == Tn)

using bf16x8 = __attribute__((ext_vector_type(8))) __bf16;
using f32x4  = __attribute__((ext_vector_type(4))) float;
using ushort8v = __attribute__((ext_vector_type(8))) unsigned short;

__device__ __forceinline__ void async16(const void* g, void* l) {
  __builtin_amdgcn_global_load_lds((const __attribute__((address_space(1))) void*)g,
                                   (__attribute__((address_space(3))) void*)l, 16, 0, 0);
}

__device__ __forceinline__ unsigned short f2bf(float v) {
  union { float f; unsigned u; } c; c.f = v;
  unsigned u = c.u;
  return (unsigned short)((u + 0x7fffu + ((u >> 16) & 1u)) >> 16);  // RNE
}

__device__ __forceinline__ float bf2f(unsigned short h) {
  union { unsigned u; float f; } c; c.u = ((unsigned)h) << 16;
  return c.f;
}

__device__ __forceinline__ float fast_sigmoid(float x) {
  float e = __builtin_amdgcn_exp2f(-1.4426950408889634f * x);
  return __builtin_amdgcn_rcpf(1.0f + e);
}
__device__ __forceinline__ float fast_tanh(float x) {
  float e = __builtin_amdgcn_exp2f(-2.8853900817779268f * x);
  return 2.0f * __builtin_amdgcn_rcpf(1.0f + e) - 1.0f;
}

// ---- 1. x -> padded bf16 (8 elems / thread) ---------------------------------
__global__ __launch_bounds__(256) void conv_x(const float* __restrict__ x,
                                              unsigned short* __restrict__ xb) {
  int idx = blockIdx.x * 256 + threadIdx.x;   // over B*(T+1)*C/8
  int c8  = idx & 63;                         // C/8 = 64
  int row = idx >> 6;                         // b*(T+1)+t
  int b   = row / (Tn + 1);
  int t   = row - b * (Tn + 1);
  ushort8v ov;
  if (t == 0) {
#pragma unroll
    for (int i = 0; i < 8; i++) ov[i] = 0;
  } else {
    const float* xp = x + (size_t)(b * Tn + t - 1) * Cn + c8 * 8;
    float4 v0 = *(const float4*)xp;
    float4 v1 = *(const float4*)(xp + 4);
    ov[0] = f2bf(v0.x); ov[1] = f2bf(v0.y); ov[2] = f2bf(v0.z); ov[3] = f2bf(v0.w);
    ov[4] = f2bf(v1.x); ov[5] = f2bf(v1.y); ov[6] = f2bf(v1.z); ov[7] = f2bf(v1.w);
  }
  *(ushort8v*)(xb + (size_t)row * Cn + c8 * 8) = ov;
}

// ---- 2. kernel -> bf16 transposed [N][K] (unchanged) ------------------------
__global__ __launch_bounds__(256) void conv_k(const float* __restrict__ kern,
                                              unsigned short* __restrict__ kT) {
  __shared__ float tile[32][33];
  int kb = blockIdx.x, nb = blockIdx.y;       // grid (32, 48)
  int tx = threadIdx.x & 31, ty = threadIdx.x >> 5;
#pragma unroll
  for (int i = 0; i < 4; i++)
    tile[ty + i * 8][tx] = kern[(size_t)(kb * 32 + ty + i * 8) * Nn + nb * 32 + tx];
  __syncthreads();
#pragma unroll
  for (int i = 0; i < 4; i++) {
    int n = nb * 32 + ty + i * 8;
    int k = kb * 32 + tx;
    kT[(size_t)n * Kn + k] = f2bf(tile[tx][ty + i * 8]);
  }
}

// ---- 3. MFMA GEMM + activation epilogue (unchanged from R5) -----------------
__global__ __launch_bounds__(256) void gemm_gates(const unsigned short* __restrict__ xb,
                                                  const unsigned short* __restrict__ kT,
                                                  const float* __restrict__ bias,
                                                  unsigned short* __restrict__ gates) {
  __shared__ unsigned short As[128 * 64];   // 16 KB
  __shared__ unsigned short Bs[128 * 64];   // 16 KB
  const int tid = threadIdx.x;
  const int m0 = blockIdx.x * 128;
  const int n0 = blockIdx.y * 128;
  const int batch = m0 / Tn;                // tiles never cross batch
  const int lane = tid & 63;
  const int w = tid >> 6, wr = w >> 1, wc = w & 1;

  const int srow = (w << 3) + (lane >> 3);        // + j*32 per call
  const int skq  = (lane & 7) ^ (lane >> 3);      // frag index this lane fetches
  const unsigned short* aStage = xb + (size_t)(m0 + batch + srow) * Cn + (skq << 3);
  const unsigned short* bStage = kT + (size_t)(n0 + srow) * Kn + (skq << 3);

  f32x4 zero = {0.f, 0.f, 0.f, 0.f};
  f32x4 acc[4][4];
#pragma unroll
  for (int i = 0; i < 4; i++)
#pragma unroll
    for (int j = 0; j < 4; j++) acc[i][j] = zero;

  const int rA0 = wr * 64 + (lane & 15);    // frag row base for A reads
  const int rB0 = wc * 64 + (lane & 15);
  const int swz = lane & 7;                 // row&7 for frag reads

  for (int k0 = 0; k0 < Kn; k0 += 64) {
#pragma unroll
    for (int j = 0; j < 4; j++) {
      async16(aStage + (size_t)(j << 5) * Cn + k0, &As[(j * 256 + tid) * 8]);
      async16(bStage + (size_t)(j << 5) * Kn + k0, &Bs[(j * 256 + tid) * 8]);
    }
    __builtin_amdgcn_s_waitcnt(0);
    __syncthreads();

#pragma unroll
    for (int ks = 0; ks < 2; ks++) {
      const int col = (((ks << 2) + (lane >> 4)) ^ swz) << 3;  // swizzled 16B col
      bf16x8 af[4], bf[4];
#pragma unroll
      for (int i = 0; i < 4; i++) {
        af[i] = *(const bf16x8*)&As[(rA0 + i * 16) * 64 + col];
        bf[i] = *(const bf16x8*)&Bs[(rB0 + i * 16) * 64 + col];
      }
#pragma unroll
      for (int i = 0; i < 4; i++)
#pragma unroll
        for (int j = 0; j < 4; j++)
          acc[i][j] = __builtin_amdgcn_mfma_f32_16x16x32_bf16(af[i], bf[j], acc[i][j], 0, 0, 0);
    }
    __syncthreads();
  }

  const int region = blockIdx.y >> 2;       // 0=z(tanh) 1=f(sig) 2=o(sig)
  const int rowB = wr * 64 + (lane >> 4) * 4;
  const int colB = wc * 64 + (lane & 15);
#pragma unroll
  for (int i = 0; i < 4; i++)
#pragma unroll
    for (int j = 0; j < 4; j++)
#pragma unroll
      for (int r = 0; r < 4; r++) {
        int mm = m0 + rowB + i * 16 + r;
        int nn = n0 + colB + j * 16;
        float g = acc[i][j][r] + bias[nn];
        float a = (region == 0) ? fast_tanh(g) : fast_sigmoid(g);
        gates[(size_t)mm * Nn + nn] = f2bf(a);
      }
}

// ---- 4. per-chunk affine (a, bv): h_end = a*h_start + bv --------------------
// grid B*NC*2 = 2048 blocks x 256 thr = 524288 threads (full occupancy);
// 1 u per thread, scalar 2B loads (one 128B txn per wave per gate).
__global__ __launch_bounds__(256) void scan_phaseA(const unsigned short* __restrict__ gates,
                                                   float* __restrict__ aArr,
                                                   float* __restrict__ bArr) {
  int chunk = blockIdx.x >> 1;              // b*NC + c
  int u = ((blockIdx.x & 1) << 8) + threadIdx.x;
  int b = chunk >> 7, c = chunk & (NC - 1);
  const unsigned short* gp = gates + (size_t)(b * Tn + c * CL) * Nn + u;
  float a = 1.0f, bv = 0.0f;
#pragma unroll
  for (int t = 0; t < CL; t++) {
    float z = bf2f(gp[0]);
    float f = bf2f(gp[Un]);
    a *= f;
    bv = f * bv + (1.0f - f) * z;
    gp += Nn;
  }
  aArr[(size_t)chunk * Un + u] = a;
  bArr[(size_t)chunk * Un + u] = bv;
}

// ---- 5. scan over chunks; 8-deep batched prefetch, separate hstart ----------
// grid 8 x 128; each thread owns 4 u's
__global__ __launch_bounds__(128) void scan_phaseB(const float* __restrict__ aArr,
                                                   const float* __restrict__ bArr,
                                                   const float* __restrict__ init,
                                                   float* __restrict__ hstart) {
  int idx = blockIdx.x * 128 + threadIdx.x; // 0..1023 = (b, u/4)
  int b = idx >> 7;
  int u0 = (idx & 127) << 2;
  float4 h = *(const float4*)(init + u0);
  for (int c0 = 0; c0 < NC; c0 += 8) {
    float4 av[8], bv[8];
#pragma unroll
    for (int j = 0; j < 8; j++) {
      size_t offc = (size_t)(b * NC + c0 + j) * Un + u0;
      av[j] = *(const float4*)(aArr + offc);
      bv[j] = *(const float4*)(bArr + offc);
    }
#pragma unroll
    for (int j = 0; j < 8; j++) {
      size_t offc = (size_t)(b * NC + c0 + j) * Un + u0;
      *(float4*)(hstart + offc) = h;        // h_start for chunk c0+j
      h.x = av[j].x * h.x + bv[j].x;
      h.y = av[j].y * h.y + bv[j].y;
      h.z = av[j].z * h.z + bv[j].z;
      h.w = av[j].w * h.w + bv[j].w;
    }
  }
}

// ---- 6. replay chunk with known h_start, apply output gate ------------------
// grid B*NC*2 = 2048 blocks x 256 thr; 1 u/thread scalar loads, f32 store.
__global__ __launch_bounds__(256) void scan_phaseC(const unsigned short* __restrict__ gates,
                                                   const float* __restrict__ hstart,
                                                   float* __restrict__ out) {
  int chunk = blockIdx.x >> 1;
  int u = ((blockIdx.x & 1) << 8) + threadIdx.x;
  int b = chunk >> 7, c = chunk & (NC - 1);
  const unsigned short* gp = gates + (size_t)(b * Tn + c * CL) * Nn + u;
  float* op = out + (size_t)(b * Tn + c * CL) * Un + u;
  float h = hstart[(size_t)chunk * Un + u];
#pragma unroll
  for (int t = 0; t < CL; t++) {
    float z = bf2f(gp[0]);
    float f = bf2f(gp[Un]);
    float o = bf2f(gp[2 * Un]);
    h = f * h + (1.0f - f) * z;
    *op = h * o;
    gp += Nn;
    op += Un;
  }
}

extern "C" void kernel_launch(void* const* d_in, const int* in_sizes, int n_in,
                              void* d_out, int out_size, void* d_ws, size_t ws_size,
                              hipStream_t stream) {
  const float* x    = (const float*)d_in[0];  // [8,2048,512]
  const float* kern = (const float*)d_in[1];  // [2,512,1536]
  const float* bias = (const float*)d_in[2];  // [1536]
  const float* init = (const float*)d_in[3];  // [1,512]
  float* out = (float*)d_out;                 // [8,2048,512]

  char* ws = (char*)d_ws;
  unsigned short* xb = (unsigned short*)ws;                      // 16.8 MB
  size_t off = (size_t)Bn * (Tn + 1) * Cn * 2;
  unsigned short* kT = (unsigned short*)(ws + off);              // 3.1 MB
  off += (size_t)Nn * Kn * 2;
  unsigned short* gates = (unsigned short*)(ws + off);           // 50.3 MB (bf16)
  off += (size_t)Mn * Nn * 2;
  float* aArr = (float*)(ws + off);  off += (size_t)Bn * NC * Un * 4;   // 2 MB
  float* bArr = (float*)(ws + off);  off += (size_t)Bn * NC * Un * 4;   // 2 MB
  float* hstart = (float*)(ws + off);                                   // 2 MB

  conv_x<<<(Bn * (Tn + 1) * Cn / 8) / 256, 256, 0, stream>>>(x, xb);
  conv_k<<<dim3(32, 48), 256, 0, stream>>>(kern, kT);
  gemm_gates<<<dim3(Mn / 128, Nn / 128), 256, 0, stream>>>(xb, kT, bias, gates);
  scan_phaseA<<<Bn * NC * 2, 256, 0, stream>>>(gates, aArr, bArr);
  scan_phaseB<<<(Bn * Un / 4) / 128, 128, 0, stream>>>(aArr, bArr, init, hstart);
  scan_phaseC<<<Bn * NC * 2, 256, 0, stream>>>(gates, hstart, out);
}